// Round 5
// baseline (49.342 us; speedup 1.0000x reference)
//
#include <hip/hip_runtime.h>
#include <hip/hip_bf16.h>
#include <math.h>

// BayesianSkipgram: V=100000, E=256, D=128, B=8192, C=10
// v5: two kernels.
//   k_cvt    : M_w/U_w/W_w fp32 -> bf16 into ws (192 KB)
//   bsg_fused: gather + emb@M_w^T + relu-sum (LDS h) + h@[U;W]^T + KL.
//              BT=8, 512 thr, 1024 blocks. h stays in LDS (no HBM round
//              trip); phase-2 weights read as bf16 from L2-hot ws; prior
//              gathers issued before the h-barrier to hide latency.
// ws layout (ushort): M_bf [0,32768), U_bf|W_bf [32768,98304). 196,608 B.

#define CTXN  10
#define DDIM  128
#define WS_M   0
#define WS_UW  32768

#define BT    8
#define ROWS  88              // r = c*8 + b (slot-major), c=0..10
#define LP    72              // A row stride (ushort): 144 B
#define ACH   (96 * LP)       // 96 rows alloc (rows 88..95 garbage, excluded)
#define HLP   264             // h row stride (ushort)

typedef short bf16x8 __attribute__((ext_vector_type(8)));
typedef float f32x4  __attribute__((ext_vector_type(4)));

__device__ __forceinline__ uint2 cvt4(float4 v) {
    union { __hip_bfloat162 h2; unsigned u; } a, b;
    a.h2 = __float22bfloat162_rn(make_float2(v.x, v.y));
    b.h2 = __float22bfloat162_rn(make_float2(v.z, v.w));
    return make_uint2(a.u, b.u);
}

__device__ __forceinline__ float softplusf(float v) {
    return fmaxf(v, 0.0f) + log1pf(expf(-fabsf(v)));
}

// ---------------- kernel 0: weight fp32 -> bf16 ----------------
__global__ __launch_bounds__(256) void k_cvt(
    const float* __restrict__ M_w, const float* __restrict__ U_w,
    const float* __restrict__ W_w, unsigned short* __restrict__ ws)
{
    int which = blockIdx.x >> 5;                       // 0:M 1:U 2:W
    int i = ((blockIdx.x & 31) << 8) | threadIdx.x;    // float4 idx 0..8191
    const float* src = (which == 0) ? M_w : (which == 1) ? U_w : W_w;
    float4 v = ((const float4*)src)[i];
    *(uint2*)&ws[which * 32768 + i * 4] = cvt4(v);
}

// ---------------- fused main kernel ----------------
__device__ __forceinline__ void load_A8(const float* __restrict__ W_emb,
                                        const int* idx_s, int k0f4, int tid,
                                        float4* sreg) {
#pragma unroll
    for (int s = 0; s < 3; ++s) {
        int it = tid + 512 * s;
        if (it < ROWS * 16) {
            int r = it >> 4, q = it & 15;
            sreg[s] = ((const float4*)W_emb)[(size_t)idx_s[r] * 64 + k0f4 + q];
        }
    }
}
__device__ __forceinline__ void write_A8(unsigned short* A, int tid,
                                         const float4* sreg) {
#pragma unroll
    for (int s = 0; s < 3; ++s) {
        int it = tid + 512 * s;
        if (it < ROWS * 16) {
            int r = it >> 4, q = it & 15;
            *(uint2*)&A[r * LP + 4 * q] = cvt4(sreg[s]);
        }
    }
}

__global__ __launch_bounds__(512, 4) void bsg_fused(
    const int* __restrict__ x, const int* __restrict__ ctx,
    const float* __restrict__ W_emb, const float* __restrict__ M_b,
    const float* __restrict__ U_b,   const float* __restrict__ W_b,
    const float* __restrict__ pmu,   const float* __restrict__ psg,
    const unsigned short* __restrict__ wsr, float* __restrict__ out)
{
    __shared__ unsigned short A_s[2 * ACH];   // 27648 B
    __shared__ unsigned short H_s[8 * HLP];   //  4224 B
    __shared__ int   idx_s[ROWS];
    __shared__ float P_s[BT * 8];

    const int tid  = threadIdx.x;
    const int b0   = blockIdx.x * BT;
    const int w    = tid >> 6;       // wave 0..7 owns d-cols 16w..16w+15
    const int lane = tid & 63;
    const int l15  = lane & 15;
    const int lg   = lane >> 4;

    if (tid < ROWS) {
        int c = tid >> 3, b = b0 + (tid & 7);
        idx_s[tid] = (c == 0) ? x[b] : ctx[b * CTXN + (c - 1)];
    }
    __syncthreads();

    // ---------------- phase 1: Rall = gathered_emb @ M_w^T ----------------
    float4 sreg[3];
    load_A8(W_emb, idx_s, 0, tid, sreg);
    write_A8(A_s, tid, sreg);

    const unsigned short* Mb_bf = wsr + WS_M;   // [128][256] bf16
    const int mrow = 16 * w + l15;
    f32x4 acc[6] = {};

#pragma unroll
    for (int ch = 0; ch < 4; ++ch) {
        if (ch < 3) load_A8(W_emb, idx_s, (ch + 1) * 16, tid, sreg);  // issue early
        __syncthreads();
        bf16x8 m0 = *(const bf16x8*)&Mb_bf[mrow * 256 + 64 * ch + 8 * lg];
        bf16x8 m1 = *(const bf16x8*)&Mb_bf[mrow * 256 + 64 * ch + 32 + 8 * lg];
        const unsigned short* Ab = A_s + (ch & 1) * ACH;
#pragma unroll
        for (int mt = 0; mt < 6; ++mt) {
            bf16x8 a0 = *(const bf16x8*)&Ab[(16 * mt + l15) * LP + 8 * lg];
            bf16x8 a1 = *(const bf16x8*)&Ab[(16 * mt + l15) * LP + 32 + 8 * lg];
            acc[mt] = __builtin_amdgcn_mfma_f32_16x16x32_bf16(a0, m0, acc[mt], 0, 0, 0);
            acc[mt] = __builtin_amdgcn_mfma_f32_16x16x32_bf16(a1, m1, acc[mt], 0, 0, 0);
        }
        if (ch < 3) write_A8(A_s + ((ch + 1) & 1) * ACH, tid, sreg);   // write late
    }

    // ---- prior gathers: issue now (only need idx_s); hide under relu-sum +
    //      barrier + phase-2 MFMA.  All lanes load (rows duplicated for lg>=2).
    float pm[4], ps[4];
#pragma unroll
    for (int q = 0; q < 4; ++q) {
        int xb = idx_s[(4 * lg + q) & 7];          // slot-0 rows = x[b0+b]
        pm[q] = pmu[(size_t)xb * DDIM + 16 * w + l15];
        ps[q] = psg[(size_t)xb * DDIM + 16 * w + l15];
    }

    // ---- relu-sum -> h (bf16, LDS rows b=0..7) ----
    // lane row = 16mt + 4lg + q ; c = row>>3, b = row&7.
    // lg<2 -> even slots (c=2mt), lg>=2 -> odd slots (c=2mt+1; mt=5 => c=11 pad).
    const int dg = 16 * w + l15;
    const float mb = M_b[dg];
    float p1[4] = {0, 0, 0, 0}, p2[4] = {0, 0, 0, 0};
#pragma unroll
    for (int mt = 0; mt < 6; ++mt) {
#pragma unroll
        for (int q = 0; q < 4; ++q) {
            float r = fmaxf(acc[mt][q] + mb, 0.0f);
            if (lg < 2) { if (mt == 0) p1[q] = r; else p2[q] += r; }
            else        { if (mt < 5)  p2[q] += r; }
        }
    }
#pragma unroll
    for (int q = 0; q < 4; ++q) {
        float other = __shfl_xor(p2[q], 32);       // pair lg0<->lg2, lg1<->lg3
        if (lg < 2) {
            int b = 4 * lg + q;
            __hip_bfloat16 t1 = __float2bfloat16(10.0f * p1[q]);   // C*relu(Rw)
            __hip_bfloat16 t2 = __float2bfloat16(p2[q] + other);   // sum_c relu(Rc)
            H_s[b * HLP + dg]       = *(unsigned short*)&t1;
            H_s[b * HLP + 128 + dg] = *(unsigned short*)&t2;
        }
    }
    __syncthreads();   // H_s visible

    // ---------------- phase 2: [mu|presig] = h @ [U;W]^T ----------------
    const unsigned short* UWb = wsr + WS_UW;   // [256][256] bf16: rows 0..127=U, 128..255=W
    const int nrow = 16 * w + l15;
    f32x4 acc2[2] = {};
#pragma unroll
    for (int ks = 0; ks < 8; ++ks) {
        bf16x8 hf = *(const bf16x8*)&H_s[(l15 & 7) * HLP + 32 * ks + 8 * lg];
        bf16x8 bu = *(const bf16x8*)&UWb[nrow * 256 + 32 * ks + 8 * lg];
        bf16x8 bw = *(const bf16x8*)&UWb[(128 + nrow) * 256 + 32 * ks + 8 * lg];
        acc2[0] = __builtin_amdgcn_mfma_f32_16x16x32_bf16(hf, bu, acc2[0], 0, 0, 0);
        acc2[1] = __builtin_amdgcn_mfma_f32_16x16x32_bf16(hf, bw, acc2[1], 0, 0, 0);
    }

    // ---------------- epilogue: bias, softplus, KL ----------------
    const float ub = U_b[16 * w + l15];
    const float wb = W_b[16 * w + l15];
#pragma unroll
    for (int q = 0; q < 4; ++q) {
        float mu = acc2[0][q] + ub;                // D row 4lg+q (valid lg<2)
        float sg = softplusf(acc2[1][q] + wb);
        float dm = mu - pm[q];
        float p  = ps[q] / sg + dm * dm / sg + logf(sg) - logf(ps[q]);
        p += __shfl_xor(p, 1);
        p += __shfl_xor(p, 2);
        p += __shfl_xor(p, 4);
        p += __shfl_xor(p, 8);
        if (l15 == 0 && lg < 2) P_s[(4 * lg + q) * 8 + w] = p;
    }
    __syncthreads();
    if (tid < BT) {
        float s = 0.0f;
#pragma unroll
        for (int k = 0; k < 8; ++k) s += P_s[tid * 8 + k];
        out[b0 + tid] = 0.5f * (s - (float)DDIM);
    }
}

extern "C" void kernel_launch(void* const* d_in, const int* in_sizes, int n_in,
                              void* d_out, int out_size, void* d_ws, size_t ws_size,
                              hipStream_t stream) {
    const int*   x     = (const int*)  d_in[0];
    const int*   ctx   = (const int*)  d_in[1];
    const float* W_emb = (const float*)d_in[2];
    const float* M_w   = (const float*)d_in[3];
    const float* M_b   = (const float*)d_in[4];
    const float* U_w   = (const float*)d_in[5];
    const float* U_b   = (const float*)d_in[6];
    const float* W_w   = (const float*)d_in[7];
    const float* W_b   = (const float*)d_in[8];
    const float* pmu   = (const float*)d_in[9];
    const float* psg   = (const float*)d_in[10];
    float* out = (float*)d_out;
    unsigned short* ws = (unsigned short*)d_ws;   // needs >= 196,608 bytes

    k_cvt<<<dim3(96), dim3(256), 0, stream>>>(M_w, U_w, W_w, ws);
    bsg_fused<<<dim3(8192 / BT), dim3(512), 0, stream>>>(
        x, ctx, W_emb, M_b, U_b, W_b, pmu, psg, ws, out);
}

// Round 6
// 47.907 us; speedup vs baseline: 1.0300x; 1.0300x over previous
//
#include <hip/hip_runtime.h>
#include <hip/hip_bf16.h>
#include <math.h>

// BayesianSkipgram: V=100000, E=256, D=128, B=8192, C=10
// v6: three kernels (v4 structure — fusion regressed in v5).
//   k_cvt : M_w/U_w/W_w fp32 -> bf16 into ws (192 KB)
//   bsg_h : gather + emb@M_w^T + relu-sum -> h[8192,256] bf16 in ws.
//           ALL gather loads (4 chunks, 12 float4/thread) + all 8 M_w
//           fragments issued upfront; program-order vmcnt = counted-wait
//           pipeline; 1 barrier/chunk; no global loads in the loop.
//   bsg_kl: h @ [U;W]^T + softplus + prior gather + KL. BT=16 (512 blocks),
//           prior gathers issued at kernel start straight from x[].
// ws layout (ushort): M_bf [0,32768), U|W_bf [32768,98304), h [98304,+2M).

#define CTXN  10
#define DDIM  128
#define WS_M   0
#define WS_UW  32768
#define WS_H   98304

typedef short bf16x8 __attribute__((ext_vector_type(8)));
typedef float f32x4  __attribute__((ext_vector_type(4)));

__device__ __forceinline__ uint2 cvt4(float4 v) {
    union { __hip_bfloat162 h2; unsigned u; } a, b;
    a.h2 = __float22bfloat162_rn(make_float2(v.x, v.y));
    b.h2 = __float22bfloat162_rn(make_float2(v.z, v.w));
    return make_uint2(a.u, b.u);
}

__device__ __forceinline__ float softplusf(float v) {
    return fmaxf(v, 0.0f) + log1pf(expf(-fabsf(v)));
}

// ---------------- kernel 0: weight fp32 -> bf16 ----------------
__global__ __launch_bounds__(256) void k_cvt(
    const float* __restrict__ M_w, const float* __restrict__ U_w,
    const float* __restrict__ W_w, unsigned short* __restrict__ ws)
{
    int which = blockIdx.x >> 5;                       // 0:M 1:U 2:W
    int i = ((blockIdx.x & 31) << 8) | threadIdx.x;    // float4 idx 0..8191
    const float* src = (which == 0) ? M_w : (which == 1) ? U_w : W_w;
    float4 v = ((const float4*)src)[i];
    *(uint2*)&ws[which * 32768 + i * 4] = cvt4(v);
}

// ---------------- kernel 1: gather + emb@M_w^T + relu-sum -> h ----------------
#define BT1   8
#define ROWS1 88              // r = c*8 + b (slot-major), c=0..10
#define LP    72              // A row stride (ushort): 144 B
#define ACH   (96 * LP)

__global__ __launch_bounds__(512, 4) void bsg_h(
    const int* __restrict__ x, const int* __restrict__ ctx,
    const float* __restrict__ W_emb, const float* __restrict__ M_b,
    const unsigned short* __restrict__ wsr, unsigned short* __restrict__ hws)
{
    __shared__ unsigned short A_s[2 * ACH];   // 27648 B
    __shared__ int idx_s[ROWS1];

    const int tid  = threadIdx.x;
    const int b0   = blockIdx.x * BT1;
    const int w    = tid >> 6;       // wave 0..7 owns d-cols 16w..16w+15
    const int lane = tid & 63;
    const int l15  = lane & 15;
    const int lg   = lane >> 4;

    if (tid < ROWS1) {
        int c = tid >> 3, b = b0 + (tid & 7);
        idx_s[tid] = (c == 0) ? x[b] : ctx[b * CTXN + (c - 1)];
    }

    // M_w B-fragments upfront (no idx dependency; L2-hot bf16 from ws)
    const unsigned short* Mb_bf = wsr + WS_M;       // [128][256]
    const int mrow = 16 * w + l15;
    bf16x8 mreg[8];
#pragma unroll
    for (int kk = 0; kk < 8; ++kk)
        mreg[kk] = *(const bf16x8*)&Mb_bf[mrow * 256 + 32 * kk + 8 * lg];

    __syncthreads();   // idx_s visible

    // ---- issue ALL gather loads (4 chunks x 3 slots) upfront ----
    float4 rr[12];
#pragma unroll
    for (int ch = 0; ch < 4; ++ch)
#pragma unroll
        for (int s = 0; s < 3; ++s) {
            int it = tid + 512 * s;
            if (it < ROWS1 * 16) {
                int r = it >> 4, q = it & 15;
                rr[ch * 3 + s] =
                    ((const float4*)W_emb)[(size_t)idx_s[r] * 64 + ch * 16 + q];
            }
        }

    // ---- 4 chunks: write(ch) -> barrier -> MFMA(ch).  One barrier/chunk;
    //      write(ch) into buf[ch&1] is safe: passing barrier(ch-1) implies all
    //      MFMA(ch-2) (same buffer) completed (program order).  vmcnt waits
    //      are counted (chunk ch write waits only for its own 3 loads).
    f32x4 acc[6] = {};
#pragma unroll
    for (int ch = 0; ch < 4; ++ch) {
        unsigned short* Ab = A_s + (ch & 1) * ACH;
#pragma unroll
        for (int s = 0; s < 3; ++s) {
            int it = tid + 512 * s;
            if (it < ROWS1 * 16) {
                int r = it >> 4, q = it & 15;
                *(uint2*)&Ab[r * LP + 4 * q] = cvt4(rr[ch * 3 + s]);
            }
        }
        __syncthreads();
        const unsigned short* Abr = A_s + (ch & 1) * ACH;
#pragma unroll
        for (int mt = 0; mt < 6; ++mt) {
            bf16x8 a0 = *(const bf16x8*)&Abr[(16 * mt + l15) * LP + 8 * lg];
            bf16x8 a1 = *(const bf16x8*)&Abr[(16 * mt + l15) * LP + 32 + 8 * lg];
            acc[mt] = __builtin_amdgcn_mfma_f32_16x16x32_bf16(a0, mreg[2 * ch],     acc[mt], 0, 0, 0);
            acc[mt] = __builtin_amdgcn_mfma_f32_16x16x32_bf16(a1, mreg[2 * ch + 1], acc[mt], 0, 0, 0);
        }
    }

    // relu-sum: lane row = 16mt+4lg+q; c = row>>3, b = row&7.
    // lg<2 -> even slots (c=2mt), lg>=2 -> odd slots (c=2mt+1; mt=5 => pad).
    const int dg = 16 * w + l15;
    const float mb = M_b[dg];
    float p1[4] = {0, 0, 0, 0}, p2[4] = {0, 0, 0, 0};
#pragma unroll
    for (int mt = 0; mt < 6; ++mt) {
#pragma unroll
        for (int q = 0; q < 4; ++q) {
            float r = fmaxf(acc[mt][q] + mb, 0.0f);
            if (lg < 2) { if (mt == 0) p1[q] = r; else p2[q] += r; }
            else        { if (mt < 5)  p2[q] += r; }
        }
    }
#pragma unroll
    for (int q = 0; q < 4; ++q) {
        float other = __shfl_xor(p2[q], 32);     // pair lg0<->lg2, lg1<->lg3
        if (lg < 2) {
            int b = 4 * lg + q;
            __hip_bfloat16 t1 = __float2bfloat16(10.0f * p1[q]);   // C*relu(Rw)
            __hip_bfloat16 t2 = __float2bfloat16(p2[q] + other);   // sum relu(Rc)
            hws[(size_t)(b0 + b) * 256 + dg]       = *(unsigned short*)&t1;
            hws[(size_t)(b0 + b) * 256 + 128 + dg] = *(unsigned short*)&t2;
        }
    }
}

// ---------------- kernel 2: h @ [U;W]^T + softplus + KL ----------------
#define BT2  16
#define HLP  264

__global__ __launch_bounds__(512, 4) void bsg_kl(
    const int* __restrict__ x, const float* __restrict__ U_b,
    const float* __restrict__ W_b, const float* __restrict__ pmu,
    const float* __restrict__ psg, const unsigned short* __restrict__ wsr,
    float* __restrict__ out)
{
    __shared__ unsigned short H_s[BT2 * HLP];   // 8448 B
    __shared__ float P_s[BT2 * 8];

    const int tid  = threadIdx.x;
    const int b0   = blockIdx.x * BT2;
    const int w    = tid >> 6;       // wave 0..7 owns d-cols 16w..16w+15
    const int lane = tid & 63;
    const int l15  = lane & 15;
    const int lg   = lane >> 4;
    const int d    = 16 * w + l15;

    // prior gathers issued upfront, straight from x[] (L2-hot, 16 values/block)
    float pm[4], ps[4];
#pragma unroll
    for (int q = 0; q < 4; ++q) {
        int xb = x[b0 + 4 * lg + q];
        pm[q] = pmu[(size_t)xb * DDIM + d];
        ps[q] = psg[(size_t)xb * DDIM + d];
    }

    // h tile copy: 512 threads x 16B = 8 KB = the whole [16][256] tile
    const unsigned short* hws = wsr + WS_H;
    {
        int r = tid >> 5, q = tid & 31;
        *(uint4*)&H_s[r * HLP + 8 * q] =
            *(const uint4*)&hws[(size_t)(b0 + r) * 256 + 8 * q];
    }
    __syncthreads();

    const unsigned short* UWb = wsr + WS_UW;    // [256][256]: 0..127=U, 128..255=W
    f32x4 acc2[2] = {};
#pragma unroll
    for (int ks = 0; ks < 8; ++ks) {
        bf16x8 hf = *(const bf16x8*)&H_s[l15 * HLP + 32 * ks + 8 * lg];
        bf16x8 bu = *(const bf16x8*)&UWb[d * 256 + 32 * ks + 8 * lg];
        bf16x8 bw = *(const bf16x8*)&UWb[(128 + d) * 256 + 32 * ks + 8 * lg];
        acc2[0] = __builtin_amdgcn_mfma_f32_16x16x32_bf16(hf, bu, acc2[0], 0, 0, 0);
        acc2[1] = __builtin_amdgcn_mfma_f32_16x16x32_bf16(hf, bw, acc2[1], 0, 0, 0);
    }

    const float ub = U_b[d], wb = W_b[d];
#pragma unroll
    for (int q = 0; q < 4; ++q) {
        int rb = 4 * lg + q;                     // batch row (C/D: row=4lg+q, col=l15)
        float mu = acc2[0][q] + ub;
        float sg = softplusf(acc2[1][q] + wb);
        float dm = mu - pm[q];
        float p  = ps[q] / sg + dm * dm / sg + logf(sg) - logf(ps[q]);
        p += __shfl_xor(p, 1);
        p += __shfl_xor(p, 2);
        p += __shfl_xor(p, 4);
        p += __shfl_xor(p, 8);
        if (l15 == 0) P_s[rb * 8 + w] = p;
    }
    __syncthreads();
    if (tid < BT2) {
        float s = 0.0f;
#pragma unroll
        for (int k = 0; k < 8; ++k) s += P_s[tid * 8 + k];
        out[b0 + tid] = 0.5f * (s - (float)DDIM);
    }
}

extern "C" void kernel_launch(void* const* d_in, const int* in_sizes, int n_in,
                              void* d_out, int out_size, void* d_ws, size_t ws_size,
                              hipStream_t stream) {
    const int*   x     = (const int*)  d_in[0];
    const int*   ctx   = (const int*)  d_in[1];
    const float* W_emb = (const float*)d_in[2];
    const float* M_w   = (const float*)d_in[3];
    const float* M_b   = (const float*)d_in[4];
    const float* U_w   = (const float*)d_in[5];
    const float* U_b   = (const float*)d_in[6];
    const float* W_w   = (const float*)d_in[7];
    const float* W_b   = (const float*)d_in[8];
    const float* pmu   = (const float*)d_in[9];
    const float* psg   = (const float*)d_in[10];
    float* out = (float*)d_out;
    unsigned short* ws = (unsigned short*)d_ws;   // needs >= 4,390,912 bytes

    k_cvt<<<dim3(96), dim3(256), 0, stream>>>(M_w, U_w, W_w, ws);
    bsg_h<<<dim3(8192 / BT1), dim3(512), 0, stream>>>(x, ctx, W_emb, M_b,
                                                      ws, ws + WS_H);
    bsg_kl<<<dim3(8192 / BT2), dim3(512), 0, stream>>>(x, U_b, W_b, pmu, psg,
                                                       ws, out);
}

// Round 7
// 44.263 us; speedup vs baseline: 1.1148x; 1.0823x over previous
//
#include <hip/hip_runtime.h>
#include <hip/hip_bf16.h>
#include <math.h>

// BayesianSkipgram: V=100000, E=256, D=128, B=8192, C=10
// v7 = v4 (best, 44.6us) + targeted fixes:
//   bsg_h : 2-chunk-ahead gather pipeline (rr[2][3], static indexing),
//           rows padded 88->96 (no predication), M-frags loaded in-loop.
//   bsg_kl: BT=16 (512 blocks = 2/CU), prior gathers hoisted to kernel start.
// ws layout (ushort): M_bf [0,32768), U|W_bf [32768,98304), h [98304,+2M).

#define CTXN  10
#define DDIM  128
#define WS_M   0
#define WS_UW  32768
#define WS_H   98304

typedef short bf16x8 __attribute__((ext_vector_type(8)));
typedef float f32x4  __attribute__((ext_vector_type(4)));

__device__ __forceinline__ uint2 cvt4(float4 v) {
    union { __hip_bfloat162 h2; unsigned u; } a, b;
    a.h2 = __float22bfloat162_rn(make_float2(v.x, v.y));
    b.h2 = __float22bfloat162_rn(make_float2(v.z, v.w));
    return make_uint2(a.u, b.u);
}

__device__ __forceinline__ float softplusf(float v) {
    return fmaxf(v, 0.0f) + log1pf(expf(-fabsf(v)));
}

// ---------------- kernel 0: weight fp32 -> bf16 ----------------
__global__ __launch_bounds__(256) void k_cvt(
    const float* __restrict__ M_w, const float* __restrict__ U_w,
    const float* __restrict__ W_w, unsigned short* __restrict__ ws)
{
    int which = blockIdx.x >> 5;                       // 0:M 1:U 2:W
    int i = ((blockIdx.x & 31) << 8) | threadIdx.x;    // float4 idx 0..8191
    const float* src = (which == 0) ? M_w : (which == 1) ? U_w : W_w;
    float4 v = ((const float4*)src)[i];
    *(uint2*)&ws[which * 32768 + i * 4] = cvt4(v);
}

// ---------------- kernel 1: gather + emb@M_w^T + relu-sum -> h ----------------
#define BT1   8
#define ROWSP 96              // padded rows (88 real, r = c*8+b slot-major, c=0..10; 88..95 pad idx 0)
#define LP    72              // A row stride (ushort): 144 B -> 2-way bank alias on b128 reads (free)
#define ACH   (ROWSP * LP)

__global__ __launch_bounds__(512, 4) void bsg_h(
    const int* __restrict__ x, const int* __restrict__ ctx,
    const float* __restrict__ W_emb, const float* __restrict__ M_b,
    const unsigned short* __restrict__ wsr, unsigned short* __restrict__ hws)
{
    __shared__ unsigned short A_s[2 * ACH];   // 27648 B
    __shared__ int idx_s[ROWSP];

    const int tid  = threadIdx.x;
    const int b0   = blockIdx.x * BT1;
    const int w    = tid >> 6;       // wave 0..7 owns d-cols 16w..16w+15
    const int lane = tid & 63;
    const int l15  = lane & 15;
    const int lg   = lane >> 4;

    if (tid < ROWSP) {
        int c = tid >> 3, b = b0 + (tid & 7);
        idx_s[tid] = (c >= 11) ? 0 : ((c == 0) ? x[b] : ctx[b * CTXN + (c - 1)]);
    }
    __syncthreads();

    // precompute this thread's staging coordinates (1536 = 3 x 512 items exact)
    const int r0 = tid >> 4, q0 = tid & 15;            // s=0 -> it=tid
    const int r1 = (tid + 512) >> 4, q1 = q0;          // q repeats every 512
    const int r2 = (tid + 1024) >> 4, q2 = q0;

    float4 rr0[3], rr1[3];
    const float4* We = (const float4*)W_emb;
#define LOADC(dst, ch)                                                          \
    {                                                                           \
        dst[0] = We[(size_t)idx_s[r0] * 64 + (ch) * 16 + q0];                   \
        dst[1] = We[(size_t)idx_s[r1] * 64 + (ch) * 16 + q1];                   \
        dst[2] = We[(size_t)idx_s[r2] * 64 + (ch) * 16 + q2];                   \
    }
#define WRITEC(Ab, src)                                                         \
    {                                                                           \
        *(uint2*)&(Ab)[r0 * LP + 4 * q0] = cvt4(src[0]);                        \
        *(uint2*)&(Ab)[r1 * LP + 4 * q1] = cvt4(src[1]);                        \
        *(uint2*)&(Ab)[r2 * LP + 4 * q2] = cvt4(src[2]);                        \
    }

    LOADC(rr0, 0);
    LOADC(rr1, 1);

    const unsigned short* Mb_bf = wsr + WS_M;          // [128][256] bf16
    const int mrow = 16 * w + l15;
    f32x4 acc[6] = {};

#pragma unroll
    for (int ch = 0; ch < 4; ++ch) {
        unsigned short* Ab = A_s + (ch & 1) * ACH;
        if (ch & 1) { WRITEC(Ab, rr1); if (ch < 2) LOADC(rr1, ch + 2); }
        else        { WRITEC(Ab, rr0); if (ch < 2) LOADC(rr0, ch + 2); }
        __syncthreads();   // buf[ch&1] ready; buf reads from ch-2 retired
        bf16x8 m0 = *(const bf16x8*)&Mb_bf[mrow * 256 + 64 * ch + 8 * lg];
        bf16x8 m1 = *(const bf16x8*)&Mb_bf[mrow * 256 + 64 * ch + 32 + 8 * lg];
        const unsigned short* Abr = A_s + (ch & 1) * ACH;
#pragma unroll
        for (int mt = 0; mt < 6; ++mt) {
            bf16x8 a0 = *(const bf16x8*)&Abr[(16 * mt + l15) * LP + 8 * lg];
            bf16x8 a1 = *(const bf16x8*)&Abr[(16 * mt + l15) * LP + 32 + 8 * lg];
            acc[mt] = __builtin_amdgcn_mfma_f32_16x16x32_bf16(a0, m0, acc[mt], 0, 0, 0);
            acc[mt] = __builtin_amdgcn_mfma_f32_16x16x32_bf16(a1, m1, acc[mt], 0, 0, 0);
        }
    }
#undef LOADC
#undef WRITEC

    // relu-sum: lane row = 16mt+4lg+q; c = row>>3, b = row&7.
    // lg<2 -> even slots (c=2mt), lg>=2 -> odd slots (c=2mt+1; mt=5 -> c=11 pad).
    const int dg = 16 * w + l15;
    const float mb = M_b[dg];
    float p1[4] = {0, 0, 0, 0}, p2[4] = {0, 0, 0, 0};
#pragma unroll
    for (int mt = 0; mt < 6; ++mt) {
#pragma unroll
        for (int q = 0; q < 4; ++q) {
            float r = fmaxf(acc[mt][q] + mb, 0.0f);
            if (lg < 2) { if (mt == 0) p1[q] = r; else p2[q] += r; }
            else        { if (mt < 5)  p2[q] += r; }
        }
    }
#pragma unroll
    for (int q = 0; q < 4; ++q) {
        float other = __shfl_xor(p2[q], 32);     // pair lg0<->lg2, lg1<->lg3
        if (lg < 2) {
            int b = 4 * lg + q;
            __hip_bfloat16 t1 = __float2bfloat16(10.0f * p1[q]);   // C*relu(Rw)
            __hip_bfloat16 t2 = __float2bfloat16(p2[q] + other);   // sum relu(Rc)
            hws[(size_t)(b0 + b) * 256 + dg]       = *(unsigned short*)&t1;
            hws[(size_t)(b0 + b) * 256 + 128 + dg] = *(unsigned short*)&t2;
        }
    }
}

// ---------------- kernel 2: h @ [U;W]^T + softplus + KL ----------------
#define BT2  16
#define HLP  264

__global__ __launch_bounds__(512, 4) void bsg_kl(
    const int* __restrict__ x, const float* __restrict__ U_b,
    const float* __restrict__ W_b, const float* __restrict__ pmu,
    const float* __restrict__ psg, const unsigned short* __restrict__ wsr,
    float* __restrict__ out)
{
    __shared__ unsigned short H_s[BT2 * HLP];   // 8448 B
    __shared__ float P_s[BT2 * 8];

    const int tid  = threadIdx.x;
    const int b0   = blockIdx.x * BT2;
    const int w    = tid >> 6;       // wave 0..7 owns d-cols 16w..16w+15
    const int lane = tid & 63;
    const int l15  = lane & 15;
    const int lg   = lane >> 4;
    const int d    = 16 * w + l15;

    // prior gathers issued upfront (x[] is L2-hot); consumed only in epilogue
    float pm[4], ps[4];
#pragma unroll
    for (int q = 0; q < 4; ++q) {
        int xb = x[b0 + 4 * lg + q];
        pm[q] = pmu[(size_t)xb * DDIM + d];
        ps[q] = psg[(size_t)xb * DDIM + d];
    }

    // h tile copy: 512 threads x 16B = 8 KB = whole [16][256] tile
    const unsigned short* hws = wsr + WS_H;
    {
        int r = tid >> 5, q = tid & 31;
        *(uint4*)&H_s[r * HLP + 8 * q] =
            *(const uint4*)&hws[(size_t)(b0 + r) * 256 + 8 * q];
    }
    __syncthreads();

    const unsigned short* UWb = wsr + WS_UW;    // [256][256]: 0..127=U, 128..255=W
    f32x4 acc2[2] = {};
#pragma unroll
    for (int ks = 0; ks < 8; ++ks) {
        bf16x8 hf = *(const bf16x8*)&H_s[l15 * HLP + 32 * ks + 8 * lg];
        bf16x8 bu = *(const bf16x8*)&UWb[d * 256 + 32 * ks + 8 * lg];
        bf16x8 bw = *(const bf16x8*)&UWb[(128 + d) * 256 + 32 * ks + 8 * lg];
        acc2[0] = __builtin_amdgcn_mfma_f32_16x16x32_bf16(hf, bu, acc2[0], 0, 0, 0);
        acc2[1] = __builtin_amdgcn_mfma_f32_16x16x32_bf16(hf, bw, acc2[1], 0, 0, 0);
    }

    const float ub = U_b[d], wb = W_b[d];
#pragma unroll
    for (int q = 0; q < 4; ++q) {
        int rb = 4 * lg + q;                    // batch row (C/D: row=4lg+q, col=l15)
        float mu = acc2[0][q] + ub;
        float sg = softplusf(acc2[1][q] + wb);
        float dm = mu - pm[q];
        float p  = ps[q] / sg + dm * dm / sg + logf(sg) - logf(ps[q]);
        p += __shfl_xor(p, 1);
        p += __shfl_xor(p, 2);
        p += __shfl_xor(p, 4);
        p += __shfl_xor(p, 8);
        if (l15 == 0) P_s[rb * 8 + w] = p;
    }
    __syncthreads();
    if (tid < BT2) {
        float s = 0.0f;
#pragma unroll
        for (int k = 0; k < 8; ++k) s += P_s[tid * 8 + k];
        out[b0 + tid] = 0.5f * (s - (float)DDIM);
    }
}

extern "C" void kernel_launch(void* const* d_in, const int* in_sizes, int n_in,
                              void* d_out, int out_size, void* d_ws, size_t ws_size,
                              hipStream_t stream) {
    const int*   x     = (const int*)  d_in[0];
    const int*   ctx   = (const int*)  d_in[1];
    const float* W_emb = (const float*)d_in[2];
    const float* M_w   = (const float*)d_in[3];
    const float* M_b   = (const float*)d_in[4];
    const float* U_w   = (const float*)d_in[5];
    const float* U_b   = (const float*)d_in[6];
    const float* W_w   = (const float*)d_in[7];
    const float* W_b   = (const float*)d_in[8];
    const float* pmu   = (const float*)d_in[9];
    const float* psg   = (const float*)d_in[10];
    float* out = (float*)d_out;
    unsigned short* ws = (unsigned short*)d_ws;   // needs >= 4,390,912 bytes

    k_cvt<<<dim3(96), dim3(256), 0, stream>>>(M_w, U_w, W_w, ws);
    bsg_h<<<dim3(8192 / BT1), dim3(512), 0, stream>>>(x, ctx, W_emb, M_b,
                                                      ws, ws + WS_H);
    bsg_kl<<<dim3(8192 / BT2), dim3(512), 0, stream>>>(x, U_b, W_b, pmu, psg,
                                                       ws, out);
}